// Round 13
// baseline (151.399 us; speedup 1.0000x reference)
//
#include <hip/hip_runtime.h>
#include <hip/hip_bf16.h>

typedef short s16x8 __attribute__((ext_vector_type(8)));
typedef float f32x16 __attribute__((ext_vector_type(16)));

#define LOG2E 1.44269504088896f

__device__ __forceinline__ unsigned bfpack2(float lo, float hi) {
  unsigned a = (unsigned)__builtin_bit_cast(unsigned short, __float2bfloat16(lo));
  unsigned b = (unsigned)__builtin_bit_cast(unsigned short, __float2bfloat16(hi));
  return a | (b << 16);
}

union U4 { unsigned u[4]; uint4 q; s16x8 v; };

// ---- prep: K,V f32 -> fragment-major bf16 tiles (16KB per (bh, kv-tile)) ----
// R8-verbatim (proven).
__global__ __launch_bounds__(128)
void prep_kv(const float* __restrict__ Kg, const float* __restrict__ Vg,
             char* __restrict__ tiles) {
  constexpr int S = 2048, Dh = 128;
  const int g  = (int)blockIdx.x;          // bh*64 + t
  const int bh = g >> 6, t = g & 63;
  const size_t base = (size_t)bh * S * Dh + (size_t)(t << 5) * Dh;
  char* out = tiles + ((size_t)g << 14);
  const int tid = (int)threadIdx.x;
  const int lane = tid & 63, half = tid >> 6;
  const int l31 = lane & 31, h5 = lane >> 5;

  {
    const float* krow = Kg + base + (size_t)l31 * Dh;
    #pragma unroll
    for (int i = 0; i < 4; ++i) {
      const int ks = half * 4 + i;
      const float* p = krow + 16 * ks + 8 * h5;
      float4 a = *(const float4*)p;
      float4 b = *(const float4*)(p + 4);
      U4 w;
      w.u[0] = bfpack2(a.x, a.y); w.u[1] = bfpack2(a.z, a.w);
      w.u[2] = bfpack2(b.x, b.y); w.u[3] = bfpack2(b.z, b.w);
      *(uint4*)(out + ks * 1024 + lane * 16) = w.q;
    }
  }
  __shared__ float lds[32][132];
  {
    const int rv = tid >> 2, q4 = tid & 3;
    const float* vrow = Vg + base + (size_t)rv * Dh;
    #pragma unroll
    for (int p = 0; p < 8; ++p)
      *(float4*)(&lds[rv][q4 * 4 + p * 16]) = *(const float4*)(vrow + q4 * 4 + p * 16);
  }
  __syncthreads();
  {
    #pragma unroll
    for (int i = 0; i < 4; ++i) {
      const int gp = half * 4 + i;
      const int ks = gp >> 2, dt = gp & 3;
      const int cv = 2 * ks + h5, d = 32 * dt + l31;
      U4 w;
      #pragma unroll
      for (int u = 0; u < 4; ++u)
        w.u[u] = bfpack2(lds[8 * cv + 2 * u][d], lds[8 * cv + 2 * u + 1][d]);
      *(uint4*)(out + 8192 + gp * 1024 + lane * 16) = w.q;
    }
  }
}

// ---- main: 1024 uniform 4-wave blocks; pair (pr,63-pr); wave w: kv t%4==w.
//      FIX vs R12: olds indexed by ABSOLUTE dt (waves of a pair write
//      disjoint dt in {2,3}/{0,1}; R12's [pair][dtL] indexing collided). ----
__global__ __launch_bounds__(256, 2)
void attn_alibi(const float* __restrict__ Qg, float* __restrict__ Og,
                const char* __restrict__ tiles) {
  constexpr int S = 2048, Dh = 128;
  const int lid  = (int)blockIdx.x;        // 0..1023
  const int xcd  = lid & 7;
  const int r8   = lid >> 3;               // 0..127
  const int bh   = xcd + 8 * (r8 & 3);     // 4 heads per XCD
  const int pr   = r8 >> 2;                // 0..31 -> pair (pr, 63-pr)
  const int head = bh & 15;

  const int tid  = (int)threadIdx.x;
  const int wq   = tid >> 6;               // wave 0..3: kv class t%4==wq
  const int lane = tid & 63, l31 = lane & 31, h5 = lane >> 5;
  const int pair = wq >> 1, hw = wq & 1;   // merge-tree coordinates

  const float c1     = 0.08838834764831845f * LOG2E;
  const float slope2 = exp2f(-0.5f * (float)(head + 1)) * LOG2E;

  const char* tb = tiles + (((size_t)bh << 6) << 14);

  float cpat[16];
  #pragma unroll
  for (int r = 0; r < 16; ++r)
    cpat[r] = slope2 * (float)((r & 3) + 8 * (r >> 2) + 4 * h5);

  __shared__ float olds[2][4][64][17];     // [pair][ABS dt][lane][reg]
  __shared__ float mlds[4][2][32];         // per-wave (m, l)

  for (int ph = 0; ph < 2; ++ph) {
    const int qt = ph ? (63 - pr) : pr;
    const int iq = (qt << 5) + l31;

    // Q fragments (all 4 waves load the same 32 rows)
    s16x8 qf[8];
    {
      const float* qrow = Qg + (size_t)bh * S * Dh + (size_t)iq * Dh;
      #pragma unroll
      for (int ks = 0; ks < 8; ++ks) {
        const float* p = qrow + 16 * ks + 8 * h5;
        float4 a = *(const float4*)p;
        float4 b = *(const float4*)(p + 4);
        U4 w;
        w.u[0] = bfpack2(a.x, a.y); w.u[1] = bfpack2(a.z, a.w);
        w.u[2] = bfpack2(b.x, b.y); w.u[3] = bfpack2(b.z, b.w);
        qf[ks] = w.v;
      }
    }

    f32x16 oacc[4];
    #pragma unroll
    for (int dt = 0; dt < 4; ++dt)
      #pragma unroll
      for (int r = 0; r < 16; ++r) oacc[dt][r] = 0.0f;
    float m2 = -3.0e38f, lsum = 0.0f;

    const int nt = qt + 1;
    for (int t = wq; t < nt; t += 4) {     // this wave's mod-4 class
      const char* kb = tb + ((size_t)t << 14) + lane * 16;
      s16x8 kf[8], vf[8];
      #pragma unroll
      for (int ks = 0; ks < 8; ++ks)
        kf[ks] = *(const s16x8*)(kb + ks * 1024);
      #pragma unroll
      for (int gp = 0; gp < 8; ++gp)
        vf[gp] = *(const s16x8*)(kb + 8192 + gp * 1024);

      // ---- S^T = K · Q^T ----
      f32x16 sc;
      #pragma unroll
      for (int r = 0; r < 16; ++r) sc[r] = 0.0f;
      __builtin_amdgcn_s_setprio(1);
      #pragma unroll
      for (int ks = 0; ks < 8; ++ks)
        sc = __builtin_amdgcn_mfma_f32_32x32x16_bf16(kf[ks], qf[ks], sc, 0, 0, 0);
      __builtin_amdgcn_s_setprio(0);

      // ---- bias + causal mask on diagonal tile only ----
      const float sb = slope2 * (float)((t << 5) - iq);
      float mloc = -3.0e38f;
      if (t != qt) {
        #pragma unroll
        for (int r = 0; r < 16; ++r) {
          float v = fmaf(sc[r], c1, sb + cpat[r]);
          sc[r] = v;
          mloc = fmaxf(mloc, v);
        }
      } else {
        #pragma unroll
        for (int r = 0; r < 16; ++r) {
          const float b = sb + cpat[r];
          float v = fmaf(sc[r], c1, b);
          v = (b > 0.0f) ? -3.0e38f : v;   // sign-exact j>i
          sc[r] = v;
          mloc = fmaxf(mloc, v);
        }
      }
      mloc = fmaxf(mloc, __shfl_xor(mloc, 32));
      if (!__all(mloc <= m2 + 8.0f)) {     // defer-max THR=8
        const float mnew = fmaxf(m2, mloc);
        const float corr = __builtin_amdgcn_exp2f(m2 - mnew);
        m2 = mnew;
        lsum *= corr;
        #pragma unroll
        for (int dt = 0; dt < 4; ++dt)
          #pragma unroll
          for (int r = 0; r < 16; ++r) oacc[dt][r] *= corr;
      }
      float ps = 0.0f;
      #pragma unroll
      for (int r = 0; r < 16; ++r) {
        const float p = __builtin_amdgcn_exp2f(sc[r] - m2);
        sc[r] = p;
        ps += p;
      }
      lsum += ps;                          // half-row partial

      // ---- pack P^T ----
      unsigned pk[4][2];
      #pragma unroll
      for (int rg = 0; rg < 4; ++rg) {
        pk[rg][0] = bfpack2(sc[4 * rg + 0], sc[4 * rg + 1]);
        pk[rg][1] = bfpack2(sc[4 * rg + 2], sc[4 * rg + 3]);
      }

      // ---- O^T += V^T · P^T ----
      #pragma unroll
      for (int ks = 0; ks < 2; ++ks) {
        unsigned a0 = pk[2 * ks][0], b0 = pk[2 * ks + 1][0];
        unsigned a1 = pk[2 * ks][1], b1 = pk[2 * ks + 1][1];
        asm("v_permlane32_swap_b32 %0, %1" : "+v"(a0), "+v"(b0));
        asm("v_permlane32_swap_b32 %0, %1" : "+v"(a1), "+v"(b1));
        U4 bf;
        bf.u[0] = a0; bf.u[1] = a1; bf.u[2] = b0; bf.u[3] = b1;
        __builtin_amdgcn_s_setprio(1);
        #pragma unroll
        for (int dt = 0; dt < 4; ++dt)
          oacc[dt] = __builtin_amdgcn_mfma_f32_32x32x16_bf16(
              vf[4 * ks + dt], bf.v, oacc[dt], 0, 0, 0);
        __builtin_amdgcn_s_setprio(0);
      }
    }

    // ================= merge tree =================
    lsum += __shfl_xor(lsum, 32);          // combine h5 halves (regalloc-safe)

    // level 1 within pairs: publish the d-half the partner finalizes,
    // indexed by ABSOLUTE dt -> waves of a pair write disjoint slots.
    #pragma unroll
    for (int dtL = 0; dtL < 2; ++dtL) {
      const int dt = 2 * (1 - hw) + dtL;
      #pragma unroll
      for (int r = 0; r < 16; ++r) olds[pair][dt][lane][r] = oacc[dt][r];
    }
    mlds[wq][0][l31] = m2;
    mlds[wq][1][l31] = lsum;
    __syncthreads();                       // B1
    const float pm = mlds[wq ^ 1][0][l31];
    const float pl = mlds[wq ^ 1][1][l31];
    const float ms1 = fmaxf(m2, pm);
    const float so1 = __builtin_amdgcn_exp2f(m2 - ms1);
    const float sp1 = __builtin_amdgcn_exp2f(pm - ms1);
    const float l1  = lsum * so1 + pl * sp1;
    #pragma unroll
    for (int dtL = 0; dtL < 2; ++dtL) {    // merge own half in-place
      const int dt = 2 * hw + dtL;         // partner published this dt
      #pragma unroll
      for (int r = 0; r < 16; ++r)
        oacc[dt][r] = oacc[dt][r] * so1 + olds[pair][dt][lane][r] * sp1;
    }
    __syncthreads();                       // B2: level-1 reads complete

    // level 2 across pairs (same hw): pair-1 publishes its merged dts,
    // disjoint by construction (wave2 -> dt 0,1; wave3 -> dt 2,3).
    if (pair == 1) {
      #pragma unroll
      for (int dtL = 0; dtL < 2; ++dtL) {
        const int dt = 2 * hw + dtL;
        #pragma unroll
        for (int r = 0; r < 16; ++r)
          olds[0][dt][lane][r] = oacc[dt][r];
      }
      mlds[wq][0][l31] = ms1;
      mlds[wq][1][l31] = l1;
    }
    __syncthreads();                       // B3
    if (pair == 0) {
      const float pm2 = mlds[wq + 2][0][l31];
      const float pl2 = mlds[wq + 2][1][l31];
      const float ms2 = fmaxf(ms1, pm2);
      const float so2 = __builtin_amdgcn_exp2f(ms1 - ms2);
      const float sp2 = __builtin_amdgcn_exp2f(pm2 - ms2);
      const float rl  = 1.0f / (l1 * so2 + pl2 * sp2);
      float* orow = Og + (size_t)bh * S * Dh + (size_t)iq * Dh;
      #pragma unroll
      for (int dtL = 0; dtL < 2; ++dtL) {
        const int dt = 2 * hw + dtL;
        #pragma unroll
        for (int rg = 0; rg < 4; ++rg) {
          float4 v;
          v.x = (oacc[dt][4 * rg + 0] * so2 + olds[0][dt][lane][4 * rg + 0] * sp2) * rl;
          v.y = (oacc[dt][4 * rg + 1] * so2 + olds[0][dt][lane][4 * rg + 1] * sp2) * rl;
          v.z = (oacc[dt][4 * rg + 2] * so2 + olds[0][dt][lane][4 * rg + 2] * sp2) * rl;
          v.w = (oacc[dt][4 * rg + 3] * so2 + olds[0][dt][lane][4 * rg + 3] * sp2) * rl;
          *(float4*)(orow + 32 * dt + 8 * rg + 4 * h5) = v;
        }
      }
    }
    __syncthreads();                       // B4: protect buffers across phases
  }
}

extern "C" void kernel_launch(void* const* d_in, const int* in_sizes, int n_in,
                              void* d_out, int out_size, void* d_ws, size_t ws_size,
                              hipStream_t stream) {
  (void)in_sizes; (void)n_in; (void)out_size; (void)ws_size;
  const float* q = (const float*)d_in[0];
  const float* k = (const float*)d_in[1];
  const float* v = (const float*)d_in[2];
  float* o = (float*)d_out;
  char* tiles = (char*)d_ws;               // 32 MiB fragment-major bf16 tiles
  prep_kv<<<dim3(2048), dim3(128), 0, stream>>>(k, v, tiles);
  attn_alibi<<<dim3(1024), dim3(256), 0, stream>>>(q, o, tiles);
}

// Round 14
// 121.701 us; speedup vs baseline: 1.2440x; 1.2440x over previous
//
#include <hip/hip_runtime.h>
#include <hip/hip_bf16.h>

typedef short s16x8 __attribute__((ext_vector_type(8)));
typedef float f32x16 __attribute__((ext_vector_type(16)));

#define LOG2E 1.44269504088896f

__device__ __forceinline__ unsigned bfpack2(float lo, float hi) {
  unsigned a = (unsigned)__builtin_bit_cast(unsigned short, __float2bfloat16(lo));
  unsigned b = (unsigned)__builtin_bit_cast(unsigned short, __float2bfloat16(hi));
  return a | (b << 16);
}

union U4 { unsigned u[4]; uint4 q; s16x8 v; };

// ---- prep: K,V f32 -> fragment-major bf16 tiles (16KB per (bh, kv-tile)) ----
// R8-verbatim (proven).
__global__ __launch_bounds__(128)
void prep_kv(const float* __restrict__ Kg, const float* __restrict__ Vg,
             char* __restrict__ tiles) {
  constexpr int S = 2048, Dh = 128;
  const int g  = (int)blockIdx.x;          // bh*64 + t
  const int bh = g >> 6, t = g & 63;
  const size_t base = (size_t)bh * S * Dh + (size_t)(t << 5) * Dh;
  char* out = tiles + ((size_t)g << 14);
  const int tid = (int)threadIdx.x;
  const int lane = tid & 63, half = tid >> 6;
  const int l31 = lane & 31, h5 = lane >> 5;

  {
    const float* krow = Kg + base + (size_t)l31 * Dh;
    #pragma unroll
    for (int i = 0; i < 4; ++i) {
      const int ks = half * 4 + i;
      const float* p = krow + 16 * ks + 8 * h5;
      float4 a = *(const float4*)p;
      float4 b = *(const float4*)(p + 4);
      U4 w;
      w.u[0] = bfpack2(a.x, a.y); w.u[1] = bfpack2(a.z, a.w);
      w.u[2] = bfpack2(b.x, b.y); w.u[3] = bfpack2(b.z, b.w);
      *(uint4*)(out + ks * 1024 + lane * 16) = w.q;
    }
  }
  __shared__ float lds[32][132];
  {
    const int rv = tid >> 2, q4 = tid & 3;
    const float* vrow = Vg + base + (size_t)rv * Dh;
    #pragma unroll
    for (int p = 0; p < 8; ++p)
      *(float4*)(&lds[rv][q4 * 4 + p * 16]) = *(const float4*)(vrow + q4 * 4 + p * 16);
  }
  __syncthreads();
  {
    #pragma unroll
    for (int i = 0; i < 4; ++i) {
      const int gp = half * 4 + i;
      const int ks = gp >> 2, dt = gp & 3;
      const int cv = 2 * ks + h5, d = 32 * dt + l31;
      U4 w;
      #pragma unroll
      for (int u = 0; u < 4; ++u)
        w.u[u] = bfpack2(lds[8 * cv + 2 * u][d], lds[8 * cv + 2 * u + 1][d]);
      *(uint4*)(out + 8192 + gp * 1024 + lane * 16) = w.q;
    }
  }
}

// ---- main: R8 structure (1024 blocks, 2 waves, pair (pr,63-pr), kv parity)
//      + K register pipeline (kA/kB, prefetch t+2 issued before QK of t)
//      + QK as two independent 4-MFMA chains.                              ----
__global__ __launch_bounds__(128, 2)
void attn_alibi(const float* __restrict__ Qg, float* __restrict__ Og,
                const char* __restrict__ tiles) {
  constexpr int S = 2048, Dh = 128;
  const int lid  = (int)blockIdx.x;        // 0..1023
  const int xcd  = lid & 7;
  const int u    = lid >> 3;               // 0..127
  const int bh   = xcd + 8 * (u >> 5);     // 4 heads per XCD
  const int pr   = u & 31;                 // pair id 0..31
  const int head = bh & 15;

  const int tid  = (int)threadIdx.x;
  const int wq   = tid >> 6;               // kv parity of this wave
  const int lane = tid & 63, l31 = lane & 31, h5 = lane >> 5;

  const float c1     = 0.08838834764831845f * LOG2E;
  const float slope2 = exp2f(-0.5f * (float)(head + 1)) * LOG2E;

  const char* tb = tiles + (((size_t)bh << 6) << 14);

  float cpat[16];
  #pragma unroll
  for (int r = 0; r < 16; ++r)
    cpat[r] = slope2 * (float)((r & 3) + 8 * (r >> 2) + 4 * h5);

  __shared__ float olds[4][64][17];        // partner O halves (abs dt indexed)
  __shared__ float mlds[2][2][32];         // per-wave (m, l)

#define LOADK(KF, T) do {                                                     \
    const char* kb_ = tb + ((size_t)(T) << 14) + lane * 16;                   \
    _Pragma("unroll")                                                         \
    for (int ks_ = 0; ks_ < 8; ++ks_)                                         \
      KF[ks_] = *(const s16x8*)(kb_ + ks_ * 1024);                            \
  } while (0)

  // One tile-step: issue V(t), issue K(t+2) into KFN, then compute on KF.
#define STEP(KF, KFN, T) do {                                                 \
    const char* vb_ = tb + ((size_t)(T) << 14) + 8192 + lane * 16;            \
    s16x8 vf[8];                                                              \
    _Pragma("unroll")                                                         \
    for (int gp_ = 0; gp_ < 8; ++gp_)                                         \
      vf[gp_] = *(const s16x8*)(vb_ + gp_ * 1024);                            \
    if ((T) + 2 < nt) LOADK(KFN, (T) + 2);                                    \
    f32x16 s0v, s1v;                                                          \
    _Pragma("unroll")                                                         \
    for (int r = 0; r < 16; ++r) { s0v[r] = 0.0f; s1v[r] = 0.0f; }            \
    __builtin_amdgcn_s_setprio(1);                                            \
    _Pragma("unroll")                                                         \
    for (int ks = 0; ks < 4; ++ks) {                                          \
      s0v = __builtin_amdgcn_mfma_f32_32x32x16_bf16(KF[ks], qf[ks], s0v, 0, 0, 0); \
      s1v = __builtin_amdgcn_mfma_f32_32x32x16_bf16(KF[ks + 4], qf[ks + 4], s1v, 0, 0, 0); \
    }                                                                         \
    __builtin_amdgcn_s_setprio(0);                                            \
    const float sb = slope2 * (float)(((T) << 5) - iq);                       \
    f32x16 sc;                                                                \
    float mloc = -3.0e38f;                                                    \
    if ((T) != qt) {                                                          \
      _Pragma("unroll")                                                       \
      for (int r = 0; r < 16; ++r) {                                          \
        float v = fmaf(s0v[r] + s1v[r], c1, sb + cpat[r]);                    \
        sc[r] = v;                                                            \
        mloc = fmaxf(mloc, v);                                                \
      }                                                                       \
    } else {                                                                  \
      _Pragma("unroll")                                                       \
      for (int r = 0; r < 16; ++r) {                                          \
        const float b = sb + cpat[r];                                         \
        float v = fmaf(s0v[r] + s1v[r], c1, b);                               \
        v = (b > 0.0f) ? -3.0e38f : v;                                        \
        sc[r] = v;                                                            \
        mloc = fmaxf(mloc, v);                                                \
      }                                                                       \
    }                                                                         \
    mloc = fmaxf(mloc, __shfl_xor(mloc, 32));                                 \
    if (!__all(mloc <= m2 + 8.0f)) {                                          \
      const float mnew = fmaxf(m2, mloc);                                     \
      const float corr = __builtin_amdgcn_exp2f(m2 - mnew);                   \
      m2 = mnew;                                                              \
      lsum *= corr;                                                           \
      _Pragma("unroll")                                                       \
      for (int dt = 0; dt < 4; ++dt)                                          \
        _Pragma("unroll")                                                     \
        for (int r = 0; r < 16; ++r) oacc[dt][r] *= corr;                     \
    }                                                                         \
    float ps = 0.0f;                                                          \
    _Pragma("unroll")                                                         \
    for (int r = 0; r < 16; ++r) {                                            \
      const float p = __builtin_amdgcn_exp2f(sc[r] - m2);                     \
      sc[r] = p;                                                              \
      ps += p;                                                                \
    }                                                                         \
    lsum += ps;                                                               \
    unsigned pk[4][2];                                                        \
    _Pragma("unroll")                                                         \
    for (int rg = 0; rg < 4; ++rg) {                                          \
      pk[rg][0] = bfpack2(sc[4 * rg + 0], sc[4 * rg + 1]);                    \
      pk[rg][1] = bfpack2(sc[4 * rg + 2], sc[4 * rg + 3]);                    \
    }                                                                         \
    _Pragma("unroll")                                                         \
    for (int ks = 0; ks < 2; ++ks) {                                          \
      unsigned a0 = pk[2 * ks][0], b0 = pk[2 * ks + 1][0];                    \
      unsigned a1 = pk[2 * ks][1], b1 = pk[2 * ks + 1][1];                    \
      asm("v_permlane32_swap_b32 %0, %1" : "+v"(a0), "+v"(b0));               \
      asm("v_permlane32_swap_b32 %0, %1" : "+v"(a1), "+v"(b1));               \
      U4 bf;                                                                  \
      bf.u[0] = a0; bf.u[1] = a1; bf.u[2] = b0; bf.u[3] = b1;                 \
      __builtin_amdgcn_s_setprio(1);                                          \
      _Pragma("unroll")                                                       \
      for (int dt = 0; dt < 4; ++dt)                                          \
        oacc[dt] = __builtin_amdgcn_mfma_f32_32x32x16_bf16(                   \
            vf[4 * ks + dt], bf.v, oacc[dt], 0, 0, 0);                        \
      __builtin_amdgcn_s_setprio(0);                                          \
    }                                                                         \
  } while (0)

  for (int ph = 0; ph < 2; ++ph) {
    const int qt = ph ? (63 - pr) : pr;    // 32-row q-tile 0..63
    const int iq = (qt << 5) + l31;

    s16x8 qf[8];
    {
      const float* qrow = Qg + (size_t)bh * S * Dh + (size_t)iq * Dh;
      #pragma unroll
      for (int ks = 0; ks < 8; ++ks) {
        const float* p = qrow + 16 * ks + 8 * h5;
        float4 a = *(const float4*)p;
        float4 b = *(const float4*)(p + 4);
        U4 w;
        w.u[0] = bfpack2(a.x, a.y); w.u[1] = bfpack2(a.z, a.w);
        w.u[2] = bfpack2(b.x, b.y); w.u[3] = bfpack2(b.z, b.w);
        qf[ks] = w.v;
      }
    }

    f32x16 oacc[4];
    #pragma unroll
    for (int dt = 0; dt < 4; ++dt)
      #pragma unroll
      for (int r = 0; r < 16; ++r) oacc[dt][r] = 0.0f;
    float m2 = -3.0e38f, lsum = 0.0f;

    const int nt = qt + 1;
    s16x8 kA[8], kB[8];
    if (wq < nt) LOADK(kA, wq);
    for (int t = wq; t < nt; t += 4) {
      STEP(kA, kB, t);
      if (t + 2 < nt) STEP(kB, kA, t + 2);
    }

    // ---- cross-wave merge: wave w finalizes d-half w (R8 verbatim) ----
    lsum += __shfl_xor(lsum, 32);
    #pragma unroll
    for (int dtL = 0; dtL < 2; ++dtL) {
      const int dt = 2 * (1 - wq) + dtL;   // partner's half (abs dt -> disjoint)
      #pragma unroll
      for (int r = 0; r < 16; ++r) olds[dt][lane][r] = oacc[dt][r];
    }
    mlds[wq][0][l31] = m2;
    mlds[wq][1][l31] = lsum;
    __syncthreads();
    {
      const float pm = mlds[1 - wq][0][l31];
      const float pl = mlds[1 - wq][1][l31];
      const float ms = fmaxf(m2, pm);
      const float so = __builtin_amdgcn_exp2f(m2 - ms);
      const float sp = __builtin_amdgcn_exp2f(pm - ms);
      const float rl = 1.0f / (lsum * so + pl * sp);
      float* orow = Og + (size_t)bh * S * Dh + (size_t)iq * Dh;
      #pragma unroll
      for (int dtL = 0; dtL < 2; ++dtL) {
        const int dt = 2 * wq + dtL;       // this wave's final half
        #pragma unroll
        for (int rg = 0; rg < 4; ++rg) {
          float4 v;
          v.x = (oacc[dt][4 * rg + 0] * so + olds[dt][lane][4 * rg + 0] * sp) * rl;
          v.y = (oacc[dt][4 * rg + 1] * so + olds[dt][lane][4 * rg + 1] * sp) * rl;
          v.z = (oacc[dt][4 * rg + 2] * so + olds[dt][lane][4 * rg + 2] * sp) * rl;
          v.w = (oacc[dt][4 * rg + 3] * so + olds[dt][lane][4 * rg + 3] * sp) * rl;
          *(float4*)(orow + 32 * dt + 8 * rg + 4 * h5) = v;
        }
      }
    }
    __syncthreads();                       // protect olds/mlds across phases
  }
#undef STEP
#undef LOADK
}

extern "C" void kernel_launch(void* const* d_in, const int* in_sizes, int n_in,
                              void* d_out, int out_size, void* d_ws, size_t ws_size,
                              hipStream_t stream) {
  (void)in_sizes; (void)n_in; (void)out_size; (void)ws_size;
  const float* q = (const float*)d_in[0];
  const float* k = (const float*)d_in[1];
  const float* v = (const float*)d_in[2];
  float* o = (float*)d_out;
  char* tiles = (char*)d_ws;               // 32 MiB fragment-major bf16 tiles
  prep_kv<<<dim3(2048), dim3(128), 0, stream>>>(k, v, tiles);
  attn_alibi<<<dim3(1024), dim3(128), 0, stream>>>(q, o, tiles);
}

// Round 16
// 101.384 us; speedup vs baseline: 1.4933x; 1.2004x over previous
//
#include <hip/hip_runtime.h>
#include <hip/hip_bf16.h>

typedef short s16x8 __attribute__((ext_vector_type(8)));
typedef float f32x16 __attribute__((ext_vector_type(16)));

#define LOG2E 1.44269504088896f

__device__ __forceinline__ unsigned bfpack2(float lo, float hi) {
  unsigned a = (unsigned)__builtin_bit_cast(unsigned short, __float2bfloat16(lo));
  unsigned b = (unsigned)__builtin_bit_cast(unsigned short, __float2bfloat16(hi));
  return a | (b << 16);
}

union U4 { unsigned u[4]; uint4 q; s16x8 v; };

// ---- prep: K,V f32 -> fragment-major bf16 tiles (16KB per (bh, kv-tile)) ----
// R8-verbatim (proven).
__global__ __launch_bounds__(128)
void prep_kv(const float* __restrict__ Kg, const float* __restrict__ Vg,
             char* __restrict__ tiles) {
  constexpr int S = 2048, Dh = 128;
  const int g  = (int)blockIdx.x;          // bh*64 + t
  const int bh = g >> 6, t = g & 63;
  const size_t base = (size_t)bh * S * Dh + (size_t)(t << 5) * Dh;
  char* out = tiles + ((size_t)g << 14);
  const int tid = (int)threadIdx.x;
  const int lane = tid & 63, half = tid >> 6;
  const int l31 = lane & 31, h5 = lane >> 5;

  {
    const float* krow = Kg + base + (size_t)l31 * Dh;
    #pragma unroll
    for (int i = 0; i < 4; ++i) {
      const int ks = half * 4 + i;
      const float* p = krow + 16 * ks + 8 * h5;
      float4 a = *(const float4*)p;
      float4 b = *(const float4*)(p + 4);
      U4 w;
      w.u[0] = bfpack2(a.x, a.y); w.u[1] = bfpack2(a.z, a.w);
      w.u[2] = bfpack2(b.x, b.y); w.u[3] = bfpack2(b.z, b.w);
      *(uint4*)(out + ks * 1024 + lane * 16) = w.q;
    }
  }
  __shared__ float lds[32][132];
  {
    const int rv = tid >> 2, q4 = tid & 3;
    const float* vrow = Vg + base + (size_t)rv * Dh;
    #pragma unroll
    for (int p = 0; p < 8; ++p)
      *(float4*)(&lds[rv][q4 * 4 + p * 16]) = *(const float4*)(vrow + q4 * 4 + p * 16);
  }
  __syncthreads();
  {
    #pragma unroll
    for (int i = 0; i < 4; ++i) {
      const int gp = half * 4 + i;
      const int ks = gp >> 2, dt = gp & 3;
      const int cv = 2 * ks + h5, d = 32 * dt + l31;
      U4 w;
      #pragma unroll
      for (int u = 0; u < 4; ++u)
        w.u[u] = bfpack2(lds[8 * cv + 2 * u][d], lds[8 * cv + 2 * u + 1][d]);
      *(uint4*)(out + 8192 + gp * 1024 + lane * 16) = w.q;
    }
  }
}

// ---- main: QBLK=128 (4 waves x 32 q-rows), KVBLK=32, LDS-shared dbuf.
//      R15 structure, staging swapped to REG-STAGING (uint4 loads +
//      ds_write_b128) -- no global_load_lds. Compute = R8 verbatim.        ----
__global__ __launch_bounds__(256, 2)
void attn_alibi(const float* __restrict__ Qg, float* __restrict__ Og,
                const char* __restrict__ tiles) {
  constexpr int S = 2048, Dh = 128;
  const int lid  = (int)blockIdx.x;        // 0..511
  const int xcd  = lid & 7;
  const int b2   = (lid >> 3) & 3;
  const int bh   = xcd + 8 * b2;           // 4 heads per XCD
  const int qb   = 15 - (lid >> 5);        // heavy-first q-block (128 rows)
  const int head = bh & 15;

  const int tid  = (int)threadIdx.x;
  const int wq   = tid >> 6;               // wave id: q sub-tile
  const int lane = tid & 63, l31 = lane & 31, h5 = lane >> 5;

  const int qtw  = 4 * qb + wq;            // this wave's 32-row q-tile index
  const int iq   = (qtw << 5) + l31;

  const float c1     = 0.08838834764831845f * LOG2E;
  const float slope2 = exp2f(-0.5f * (float)(head + 1)) * LOG2E;

  const char* tb = tiles + (((size_t)bh << 6) << 14);

  float cpat[16];
  #pragma unroll
  for (int r = 0; r < 16; ++r)
    cpat[r] = slope2 * (float)((r & 3) + 8 * (r >> 2) + 4 * h5);

  __shared__ __align__(16) char smem[32768];   // 2 x 16KB tile dbuf

  // Q fragments (R8 pattern)
  s16x8 qf[8];
  {
    const float* qrow = Qg + (size_t)bh * S * Dh + (size_t)iq * Dh;
    #pragma unroll
    for (int ks = 0; ks < 8; ++ks) {
      const float* p = qrow + 16 * ks + 8 * h5;
      float4 a = *(const float4*)p;
      float4 b = *(const float4*)(p + 4);
      U4 w;
      w.u[0] = bfpack2(a.x, a.y); w.u[1] = bfpack2(a.z, a.w);
      w.u[2] = bfpack2(b.x, b.y); w.u[3] = bfpack2(b.z, b.w);
      qf[ks] = w.v;
    }
  }

  f32x16 oacc[4];
  #pragma unroll
  for (int dt = 0; dt < 4; ++dt)
    #pragma unroll
    for (int r = 0; r < 16; ++r) oacc[dt][r] = 0.0f;
  float m2 = -3.0e38f, lsum = 0.0f;

  // reg-staging: wave wq stages its contiguous 4KB quarter of the 16KB tile.
  // 64 lanes x 16B x 4 chunks; plain global loads + ds_write_b128.
#define STAGE(buf, tt) do {                                                   \
    const char* src_ = tb + ((size_t)(tt) << 14) + wq * 4096 + lane * 16;     \
    char* dst_ = smem + ((buf) << 14) + wq * 4096 + lane * 16;                \
    uint4 r0_ = *(const uint4*)(src_);                                        \
    uint4 r1_ = *(const uint4*)(src_ + 1024);                                 \
    uint4 r2_ = *(const uint4*)(src_ + 2048);                                 \
    uint4 r3_ = *(const uint4*)(src_ + 3072);                                 \
    *(uint4*)(dst_)        = r0_;                                             \
    *(uint4*)(dst_ + 1024) = r1_;                                             \
    *(uint4*)(dst_ + 2048) = r2_;                                             \
    *(uint4*)(dst_ + 3072) = r3_;                                             \
  } while (0)

  const int nt = 4 * qb + 4;               // block covers kv tiles 0..nt-1
  STAGE(0, 0);

  for (int t = 0; t < nt; ++t) {
    __syncthreads();                       // lgkm drained: buf[t&1] complete
    if (t + 1 < nt) STAGE((t + 1) & 1, t + 1);  // writes buf[(t+1)&1], disjoint
    if (t > qtw) continue;                 // wave-uniform causal skip
    const char* kbuf = smem + ((t & 1) << 14);

    // ---- fragments from shared LDS tile ----
    s16x8 kf[8], vf[8];
    #pragma unroll
    for (int ks = 0; ks < 8; ++ks)
      kf[ks] = *(const s16x8*)(kbuf + ks * 1024 + lane * 16);
    #pragma unroll
    for (int gp = 0; gp < 8; ++gp)
      vf[gp] = *(const s16x8*)(kbuf + 8192 + gp * 1024 + lane * 16);

    // ---- S^T = K · Q^T ----
    f32x16 sc;
    #pragma unroll
    for (int r = 0; r < 16; ++r) sc[r] = 0.0f;
    __builtin_amdgcn_s_setprio(1);
    #pragma unroll
    for (int ks = 0; ks < 8; ++ks)
      sc = __builtin_amdgcn_mfma_f32_32x32x16_bf16(kf[ks], qf[ks], sc, 0, 0, 0);
    __builtin_amdgcn_s_setprio(0);

    // ---- bias + causal mask on this wave's diagonal tile only ----
    const float sb = slope2 * (float)((t << 5) - iq);
    float mloc = -3.0e38f;
    if (t != qtw) {
      #pragma unroll
      for (int r = 0; r < 16; ++r) {
        float v = fmaf(sc[r], c1, sb + cpat[r]);
        sc[r] = v;
        mloc = fmaxf(mloc, v);
      }
    } else {
      #pragma unroll
      for (int r = 0; r < 16; ++r) {
        const float b = sb + cpat[r];
        float v = fmaf(sc[r], c1, b);
        v = (b > 0.0f) ? -3.0e38f : v;     // sign-exact j>i
        sc[r] = v;
        mloc = fmaxf(mloc, v);
      }
    }
    mloc = fmaxf(mloc, __shfl_xor(mloc, 32));
    if (!__all(mloc <= m2 + 8.0f)) {       // defer-max THR=8
      const float mnew = fmaxf(m2, mloc);
      const float corr = __builtin_amdgcn_exp2f(m2 - mnew);
      m2 = mnew;
      lsum *= corr;
      #pragma unroll
      for (int dt = 0; dt < 4; ++dt)
        #pragma unroll
        for (int r = 0; r < 16; ++r) oacc[dt][r] *= corr;
    }
    float ps = 0.0f;
    #pragma unroll
    for (int r = 0; r < 16; ++r) {
      const float p = __builtin_amdgcn_exp2f(sc[r] - m2);
      sc[r] = p;
      ps += p;
    }
    lsum += ps;                            // half-row partial

    // ---- pack P^T ----
    unsigned pk[4][2];
    #pragma unroll
    for (int rg = 0; rg < 4; ++rg) {
      pk[rg][0] = bfpack2(sc[4 * rg + 0], sc[4 * rg + 1]);
      pk[rg][1] = bfpack2(sc[4 * rg + 2], sc[4 * rg + 3]);
    }

    // ---- O^T += V^T · P^T ----
    #pragma unroll
    for (int ks = 0; ks < 2; ++ks) {
      unsigned a0 = pk[2 * ks][0], b0 = pk[2 * ks + 1][0];
      unsigned a1 = pk[2 * ks][1], b1 = pk[2 * ks + 1][1];
      asm("v_permlane32_swap_b32 %0, %1" : "+v"(a0), "+v"(b0));
      asm("v_permlane32_swap_b32 %0, %1" : "+v"(a1), "+v"(b1));
      U4 bf;
      bf.u[0] = a0; bf.u[1] = a1; bf.u[2] = b0; bf.u[3] = b1;
      __builtin_amdgcn_s_setprio(1);
      #pragma unroll
      for (int dt = 0; dt < 4; ++dt)
        oacc[dt] = __builtin_amdgcn_mfma_f32_32x32x16_bf16(
            vf[4 * ks + dt], bf.v, oacc[dt], 0, 0, 0);
      __builtin_amdgcn_s_setprio(0);
    }
  }
#undef STAGE

  // ---- epilogue: no merge needed; wave owns its rows ----
  lsum += __shfl_xor(lsum, 32);            // combine h5 halves (regalloc-safe)
  const float rl = 1.0f / lsum;
  float* orow = Og + (size_t)bh * S * Dh + (size_t)iq * Dh;
  #pragma unroll
  for (int dt = 0; dt < 4; ++dt)
    #pragma unroll
    for (int rg = 0; rg < 4; ++rg) {
      float4 v;
      v.x = oacc[dt][4 * rg + 0] * rl;
      v.y = oacc[dt][4 * rg + 1] * rl;
      v.z = oacc[dt][4 * rg + 2] * rl;
      v.w = oacc[dt][4 * rg + 3] * rl;
      *(float4*)(orow + 32 * dt + 8 * rg + 4 * h5) = v;
    }
}

extern "C" void kernel_launch(void* const* d_in, const int* in_sizes, int n_in,
                              void* d_out, int out_size, void* d_ws, size_t ws_size,
                              hipStream_t stream) {
  (void)in_sizes; (void)n_in; (void)out_size; (void)ws_size;
  const float* q = (const float*)d_in[0];
  const float* k = (const float*)d_in[1];
  const float* v = (const float*)d_in[2];
  float* o = (float*)d_out;
  char* tiles = (char*)d_ws;               // 32 MiB fragment-major bf16 tiles
  prep_kv<<<dim3(2048), dim3(128), 0, stream>>>(k, v, tiles);
  attn_alibi<<<dim3(512), dim3(256), 0, stream>>>(q, o, tiles);
}